// Round 2
// baseline (127.180 us; speedup 1.0000x reference)
//
#include <hip/hip_runtime.h>
#include <stdint.h>
#include <math.h>

typedef __attribute__((ext_vector_type(8))) short short8;
typedef __attribute__((ext_vector_type(16))) float f32x16;

#define DEVI static __device__ __forceinline__

constexpr int D  = 256;   // feature dim
constexpr int MT = 128;   // z chunk rows
constexpr int KT = 128;   // e tile cols

// LDS layout (bytes)
constexpr int OFF_EBUF  = MT * D * 2;             // 65536
constexpr int OFF_ZTERM = OFF_EBUF + KT * D * 2;  // 131072
constexpr int OFF_PMAX  = OFF_ZTERM + MT * 4;     // 131584
constexpr int OFF_PSUM  = OFF_PMAX + 2 * KT * 4;  // 132608
constexpr int SMEM_BYTES = OFF_PSUM + 2 * KT * 4; // 133632

// workspace layout (bytes)
constexpr size_t WS_EBF   = 0;        // 512*256 bf16      = 262144
constexpr size_t WS_ETERM = 262144;   // 512 f32           = 2048
constexpr size_t WS_WMAX  = 264192;   // 256*512 f32       = 524288
constexpr size_t WS_WSUM  = 788480;   // 256*512 f32       = 524288
constexpr size_t WS_PART  = 1312768;  // 128 f32

DEVI unsigned int f2bf(float f) {
  unsigned int u = __float_as_uint(f);
  return (u + 0x7fffu + ((u >> 16) & 1u)) >> 16;  // RNE f32->bf16 (finite)
}
DEVI float shflx(float v, int m) { return __shfl_xor(v, m, 64); }

// ---- prep: e -> bf16(a*e) linear [512][256] + eterm = -a/2*||e_row||^2 ----
__global__ void prep_e(const float* __restrict__ e, const float* __restrict__ lsp,
                       unsigned short* __restrict__ ebf, float* __restrict__ eterm) {
  const int t = threadIdx.x;
  const int row = blockIdx.x * 64 + (t >> 3);  // 8 blocks x 64 rows
  const int c8 = t & 7;                        // 8 threads per row, 32 f32 each
  const float a = __expf(-2.0f * lsp[0]);
  const float* s = e + (size_t)row * D + c8 * 32;
  float sq = 0.0f;
  unsigned int w[16];
#pragma unroll
  for (int i = 0; i < 8; ++i) {
    float4 x = *(const float4*)(s + i * 4);
    sq += x.x * x.x + x.y * x.y + x.z * x.z + x.w * x.w;
    w[2 * i]     = f2bf(a * x.x) | (f2bf(a * x.y) << 16);
    w[2 * i + 1] = f2bf(a * x.z) | (f2bf(a * x.w) << 16);
  }
  sq += shflx(sq, 1); sq += shflx(sq, 2); sq += shflx(sq, 4);  // 8-thread group (aligned)
  uint4* dst = (uint4*)((char*)ebf + (size_t)row * 512 + c8 * 64);
#pragma unroll
  for (int i = 0; i < 4; ++i) {
    uint4 pk; pk.x = w[4 * i]; pk.y = w[4 * i + 1]; pk.z = w[4 * i + 2]; pk.w = w[4 * i + 3];
    dst[i] = pk;
  }
  if (c8 == 0) eterm[row] = -0.5f * a * sq;
}

// ---- main: 256 blocks, block = 256 z-rows; per chunk (128 rows) x 4 e-tiles ----
// Writes per-block per-column partial (max, sum) to wmax/wsum.
__global__ __launch_bounds__(512, 1)
void lse_main(const float* __restrict__ z, const uint4* __restrict__ ebf,
              const float* __restrict__ lsp, float* __restrict__ wmax,
              float* __restrict__ wsum) {
  extern __shared__ char smem[];
  char*  zbuf  = smem;
  char*  ebuf  = smem + OFF_EBUF;
  float* zterm = (float*)(smem + OFF_ZTERM);
  float* pmaxb = (float*)(smem + OFF_PMAX);
  float* psumb = (float*)(smem + OFF_PSUM);

  const int tid = threadIdx.x;
  const int wid = tid >> 6;
  const int lane = tid & 63;
  const int hi  = lane >> 5;
  const int l31 = lane & 31;
  const int bx  = blockIdx.x;
  const size_t rowbase = (size_t)bx * 256;
  const float a = __expf(-2.0f * lsp[0]);
  const int wr = wid >> 2;  // 0..1 : 64-row half of chunk
  const int wc = wid & 3;   // 0..3 : 32-col slice of e-tile

  float4 zr[16];  // z prefetch regs (one chunk: 16 rows/wave * 256 cols)
  uint4  er[8];   // e prefetch regs (one tile slice)
  float rm[4] = {-1e30f, -1e30f, -1e30f, -1e30f};
  float rs[4] = {0.0f, 0.0f, 0.0f, 0.0f};

  auto Z_PRE = [&](int mc) {
#pragma unroll
    for (int p = 0; p < 8; ++p) {
      int cr = wid * 16 + p * 2 + hi;
      const float* s = z + (rowbase + mc * MT + cr) * (size_t)D + l31 * 8;
      zr[2 * p]     = *(const float4*)s;
      zr[2 * p + 1] = *(const float4*)(s + 4);
    }
  };
  auto Z_COMMIT = [&]() {
#pragma unroll
    for (int p = 0; p < 8; ++p) {
      int cr = wid * 16 + p * 2 + hi;
      float4 x0 = zr[2 * p], x1 = zr[2 * p + 1];
      float sq = x0.x * x0.x + x0.y * x0.y + x0.z * x0.z + x0.w * x0.w +
                 x1.x * x1.x + x1.y * x1.y + x1.z * x1.z + x1.w * x1.w;
      sq += shflx(sq, 1); sq += shflx(sq, 2); sq += shflx(sq, 4);
      sq += shflx(sq, 8); sq += shflx(sq, 16);
      uint4 pk;
      pk.x = f2bf(x0.x) | (f2bf(x0.y) << 16);
      pk.y = f2bf(x0.z) | (f2bf(x0.w) << 16);
      pk.z = f2bf(x1.x) | (f2bf(x1.y) << 16);
      pk.w = f2bf(x1.z) | (f2bf(x1.w) << 16);
      int byte = (cr * 512 + l31 * 16) ^ ((cr & 7) << 4);
      *(uint4*)(zbuf + byte) = pk;
      if (l31 == 0) zterm[cr] = -0.5f * a * sq;
    }
  };
  auto E_PRE = [&](int et) {
#pragma unroll
    for (int p = 0; p < 8; ++p) {
      int cr = wid * 16 + p * 2 + hi;
      er[p] = ebf[(et * KT + cr) * 32 + l31];
    }
  };
  auto E_COMMIT = [&]() {
#pragma unroll
    for (int p = 0; p < 8; ++p) {
      int cr = wid * 16 + p * 2 + hi;
      int byte = (cr * 512 + l31 * 16) ^ ((cr & 7) << 4);
      *(uint4*)(ebuf + byte) = er[p];
    }
  };

  // prologue: stage chunk 0 + tile 0
  Z_PRE(0);
  E_PRE(0);
  Z_COMMIT();
  E_COMMIT();
  __syncthreads();

  for (int mc = 0; mc < 2; ++mc) {
#pragma unroll
    for (int et = 0; et < 4; ++et) {
      const bool last = (mc == 1) && (et == 3);
      if (!last) E_PRE((et + 1) & 3);      // issue next e-tile loads early
      if (mc == 0 && et == 2) Z_PRE(1);    // issue chunk-1 z loads 2 phases early

      f32x16 acc0, acc1;
#pragma unroll
      for (int i = 0; i < 16; ++i) { acc0[i] = 0.0f; acc1[i] = 0.0f; }
#pragma unroll
      for (int ks = 0; ks < 16; ++ks) {
        const int kb = ks * 32 + hi * 16;
        int r0 = wr * 64 + l31;
        short8 fa0 = *(const short8*)(zbuf + ((r0 * 512 + kb) ^ ((r0 & 7) << 4)));
        int r1 = r0 + 32;
        short8 fa1 = *(const short8*)(zbuf + ((r1 * 512 + kb) ^ ((r1 & 7) << 4)));
        int rb = wc * 32 + l31;
        short8 fb = *(const short8*)(ebuf + ((rb * 512 + kb) ^ ((rb & 7) << 4)));
        acc0 = __builtin_amdgcn_mfma_f32_32x32x16_bf16(fa0, fb, acc0, 0, 0, 0);
        acc1 = __builtin_amdgcn_mfma_f32_32x32x16_bf16(fa1, fb, acc1, 0, 0, 0);
      }

      // epilogue: per-column max/sumexp over this wave's 64 rows
      float v[32];
#pragma unroll
      for (int r = 0; r < 16; ++r) {
        int rr = (r & 3) + 8 * (r >> 2) + 4 * hi;
        v[r]      = acc0[r] + zterm[wr * 64 + rr];
        v[16 + r] = acc1[r] + zterm[wr * 64 + 32 + rr];
      }
      float mx = v[0];
#pragma unroll
      for (int i = 1; i < 32; ++i) mx = fmaxf(mx, v[i]);
      mx = fmaxf(mx, shflx(mx, 32));
      float sme = 0.0f;
#pragma unroll
      for (int i = 0; i < 32; ++i) sme += __expf(v[i] - mx);
      sme += shflx(sme, 32);
      if (hi == 0) {
        pmaxb[wr * KT + wc * 32 + l31] = mx;
        psumb[wr * KT + wc * 32 + l31] = sme;
      }
      __syncthreads();  // pmax/psum visible; all zbuf/ebuf reads done

      if (tid < KT) {  // merge both row-halves into running state for col et*128+tid
        float p0 = pmaxb[tid], p1 = pmaxb[KT + tid];
        float s0 = psumb[tid], s1 = psumb[KT + tid];
        float nm = fmaxf(rm[et], fmaxf(p0, p1));
        rs[et] = rs[et] * __expf(rm[et] - nm) + s0 * __expf(p0 - nm) + s1 * __expf(p1 - nm);
        rm[et] = nm;
      }
      if (!last) E_COMMIT();              // write next e-tile into ebuf
      if (mc == 0 && et == 3) Z_COMMIT(); // convert+write chunk 1 into zbuf
      __syncthreads();                    // commits visible before next phase
    }
  }

  if (tid < KT) {
#pragma unroll
    for (int et = 0; et < 4; ++et) {
      wmax[(size_t)bx * 512 + et * KT + tid] = rm[et];
      wsum[(size_t)bx * 512 + et * KT + tid] = rs[et];
    }
  }
}

// ---- merge the two half-blocks of each b, add eterm, sum over k ----
__global__ void merge_b(const float* __restrict__ wmax, const float* __restrict__ wsum,
                        const float* __restrict__ eterm, float* __restrict__ partial) {
  __shared__ float sh[512];
  const int b = blockIdx.x, t = threadIdx.x;
  float m0 = wmax[(size_t)(2 * b) * 512 + t];
  float m1 = wmax[(size_t)(2 * b + 1) * 512 + t];
  float s0 = wsum[(size_t)(2 * b) * 512 + t];
  float s1 = wsum[(size_t)(2 * b + 1) * 512 + t];
  float nm = fmaxf(m0, m1);
  float s = s0 * __expf(m0 - nm) + s1 * __expf(m1 - nm);
  sh[t] = nm + logf(s) + eterm[t];
  __syncthreads();
  for (int st = 256; st > 0; st >>= 1) {
    if (t < st) sh[t] += sh[t + st];
    __syncthreads();
  }
  if (t == 0) partial[b] = sh[0];
}

__global__ void final_k(const float* __restrict__ partial,
                        const float* __restrict__ lsp, float* __restrict__ out) {
  __shared__ float sh[128];
  const int t = threadIdx.x;
  sh[t] = partial[t];
  __syncthreads();
  for (int st = 64; st > 0; st >>= 1) {
    if (t < st) sh[t] += sh[t + st];
    __syncthreads();
  }
  if (t == 0) {
    float ls = lsp[0];
    out[0] = -sh[0] / 65536.0f + 128.0f * (2.0f * ls - 1.0f) + logf(512.0f);
  }
}

extern "C" void kernel_launch(void* const* d_in, const int* in_sizes, int n_in,
                              void* d_out, int out_size, void* d_ws, size_t ws_size,
                              hipStream_t stream) {
  const float* z   = (const float*)d_in[0];
  const float* e   = (const float*)d_in[1];
  const float* lsp = (const float*)d_in[2];
  float* out = (float*)d_out;
  char* ws = (char*)d_ws;
  unsigned short* ebf = (unsigned short*)(ws + WS_EBF);
  float* eterm   = (float*)(ws + WS_ETERM);
  float* wmax    = (float*)(ws + WS_WMAX);
  float* wsum    = (float*)(ws + WS_WSUM);
  float* partial = (float*)(ws + WS_PART);

  hipFuncSetAttribute(reinterpret_cast<const void*>(lse_main),
                      hipFuncAttributeMaxDynamicSharedMemorySize, SMEM_BYTES);
  prep_e<<<dim3(8), dim3(512), 0, stream>>>(e, lsp, ebf, eterm);
  lse_main<<<dim3(256), dim3(512), SMEM_BYTES, stream>>>(z, (const uint4*)ebf, lsp, wmax, wsum);
  merge_b<<<dim3(128), dim3(512), 0, stream>>>(wmax, wsum, eterm, partial);
  final_k<<<dim3(1), dim3(128), 0, stream>>>(partial, lsp, out);
}

// Round 3
// 77.894 us; speedup vs baseline: 1.6327x; 1.6327x over previous
//
#include <hip/hip_runtime.h>
#include <stdint.h>
#include <math.h>

typedef __attribute__((ext_vector_type(8))) short short8;
typedef __attribute__((ext_vector_type(16))) float f32x16;

#define DEVI static __device__ __forceinline__

constexpr int D  = 256;   // feature dim
constexpr int KT = 64;    // e-tile cols per phase
constexpr int NT = 8;     // 512 / KT phases
constexpr int TB = KT * D * 2;            // 32768 bytes per e-tile

// LDS layout
constexpr int OFF_ZT = 2 * TB;            // zterm: 128 f32
constexpr int OFF_PM = OFF_ZT + 512;      // pmax [2 parity][4 mw][64]
constexpr int OFF_PS = OFF_PM + 2048;     // psum [2][4][64]
constexpr int SMEM_BYTES = OFF_PS + 2048; // 70144 -> 2 blocks/CU

// ws layout (bytes)
constexpr size_t WS_EIMG  = 0;                     // 8 tiles x 32768 = 262144
constexpr size_t WS_ETERM = 262144;                // 512 f32
constexpr size_t WS_WMAX  = 264192;                // 512 blk x 512 col f32 = 1 MB
constexpr size_t WS_WSUM  = WS_WMAX + 1048576;     // 1 MB
constexpr size_t WS_PART  = WS_WSUM + 1048576;     // 128 f32

DEVI unsigned int f2bf(float f) {
  unsigned int u = __float_as_uint(f);
  return (u + 0x7fffu + ((u >> 16) & 1u)) >> 16;  // RNE f32->bf16 (finite)
}
DEVI float shflx(float v, int m) { return __shfl_xor(v, m, 64); }

// ---- prep: e -> swizzled bf16(a*e) tile images + eterm = -a/2*||e_row||^2 ----
// 8 blocks (one per tile) x 256 threads; thread = (col c = t>>2, quarter q = t&3).
__global__ void prep_e(const float* __restrict__ e, const float* __restrict__ lsp,
                       char* __restrict__ eimg, float* __restrict__ eterm) {
  const int et = blockIdx.x, t = threadIdx.x;
  const int c = t >> 2, q = t & 3;
  const int gc = et * 64 + c;
  const float a = __expf(-2.0f * lsp[0]);
  const float* s = e + (size_t)gc * D + q * 64;
  float sq = 0.0f;
  unsigned int w[32];
#pragma unroll
  for (int i = 0; i < 16; ++i) {
    float4 x = *(const float4*)(s + i * 4);
    sq += x.x * x.x + x.y * x.y + x.z * x.z + x.w * x.w;
    w[2 * i]     = f2bf(a * x.x) | (f2bf(a * x.y) << 16);
    w[2 * i + 1] = f2bf(a * x.z) | (f2bf(a * x.w) << 16);
  }
  sq += shflx(sq, 1); sq += shflx(sq, 2);  // 4-thread group (lane-aligned)
  char* base = eimg + (size_t)et * TB;
#pragma unroll
  for (int g = 0; g < 8; ++g) {
    int j = q * 8 + g;  // 16B granule within the col's 512B row
    int phys = (c * 512 + j * 16) ^ ((c & 7) << 4);  // pre-apply read swizzle
    uint4 pk; pk.x = w[4 * g]; pk.y = w[4 * g + 1];
    pk.z = w[4 * g + 2]; pk.w = w[4 * g + 3];
    *(uint4*)(base + phys) = pk;
  }
  if (q == 0) eterm[gc] = -0.5f * a * sq;
}

// ---- main: 512 blocks x 512 thr; block owns 128 z-rows (read ONCE from HBM,
// held in MFMA A-fragments: 64 VGPR). 8 phases over 64-col e-tiles. ----
__global__ __launch_bounds__(512, 4)
void lse_main(const float* __restrict__ z, const uint4* __restrict__ eimg,
              const float* __restrict__ lsp, float* __restrict__ wmax,
              float* __restrict__ wsum) {
  extern __shared__ char smem[];
  float* zterm = (float*)(smem + OFF_ZT);
  float* pmaxb = (float*)(smem + OFF_PM);
  float* psumb = (float*)(smem + OFF_PS);

  const int tid = threadIdx.x;
  const int wid = tid >> 6, lane = tid & 63;
  const int hi = lane >> 5, l31 = lane & 31;
  const int mw = wid >> 1;   // 0..3 : 32-row slice
  const int kw = wid & 1;    // 0..1 : 32-col slice of the 64-col tile
  const int bx = blockIdx.x;
  const float a = __expf(-2.0f * lsp[0]);

  uint4 er[4];  // e-tile staging regs (issue-early / commit-late)
  auto E_PRE = [&](int et) {
#pragma unroll
    for (int p = 0; p < 4; ++p) er[p] = eimg[et * 2048 + p * 512 + tid];
  };
  auto E_COMMIT = [&](int buf) {
#pragma unroll
    for (int p = 0; p < 4; ++p)
      *(uint4*)(smem + buf * TB + p * 8192 + tid * 16) = er[p];
  };

  E_PRE(0);  // issue tile-0 loads first; they land during z staging

  // z -> A-fragments: lane holds row (bx*128 + mw*32 + l31), cols hi*8 + s*16 ..+8
  short8 A[16];
  const float* zs = z + ((size_t)bx * 128 + mw * 32 + l31) * D + hi * 8;
  float sq = 0.0f;
#pragma unroll
  for (int s = 0; s < 16; ++s) {
    float4 x0 = *(const float4*)(zs + s * 16);
    float4 x1 = *(const float4*)(zs + s * 16 + 4);
    sq += x0.x * x0.x + x0.y * x0.y + x0.z * x0.z + x0.w * x0.w +
          x1.x * x1.x + x1.y * x1.y + x1.z * x1.z + x1.w * x1.w;
    uint4 pk;
    pk.x = f2bf(x0.x) | (f2bf(x0.y) << 16);
    pk.y = f2bf(x0.z) | (f2bf(x0.w) << 16);
    pk.z = f2bf(x1.x) | (f2bf(x1.y) << 16);
    pk.w = f2bf(x1.z) | (f2bf(x1.w) << 16);
    A[s] = __builtin_bit_cast(short8, pk);
  }
  sq += shflx(sq, 32);  // combine the two col-halves of the row
  if (hi == 0) zterm[mw * 32 + l31] = -0.5f * a * sq;

  E_COMMIT(0);
  __syncthreads();

  for (int et = 0; et < NT; ++et) {
    const int cur = et & 1;
    if (et + 1 < NT) E_PRE(et + 1);  // async: lands during this phase's MFMA

    f32x16 acc;
#pragma unroll
    for (int i = 0; i < 16; ++i) acc[i] = 0.0f;

    const int cbase = cur * TB + (kw * 32 + l31) * 512 + hi * 16;
    const int key = (l31 & 7) << 4;
#pragma unroll
    for (int s = 0; s < 16; ++s) {
      short8 B = *(const short8*)(smem + ((cbase + s * 32) ^ key));
      acc = __builtin_amdgcn_mfma_f32_32x32x16_bf16(A[s], B, acc, 0, 0, 0);
    }

    // per-column LSE partial over this wave's 32 rows (in-place, no v[] array)
    float mx = -1e30f;
#pragma unroll
    for (int r = 0; r < 16; ++r) {
      acc[r] += zterm[mw * 32 + (r & 3) + 8 * (r >> 2) + 4 * hi];  // broadcast read
      mx = fmaxf(mx, acc[r]);
    }
    mx = fmaxf(mx, shflx(mx, 32));
    float sme = 0.0f;
#pragma unroll
    for (int r = 0; r < 16; ++r) sme += __expf(acc[r] - mx);
    sme += shflx(sme, 32);
    if (hi == 0) {
      pmaxb[cur * 256 + mw * 64 + kw * 32 + l31] = mx;
      psumb[cur * 256 + mw * 64 + kw * 32 + l31] = sme;
    }
    if (et + 1 < NT) E_COMMIT(cur ^ 1);  // write next tile (other buffer)
    __syncthreads();  // pmax/psum + committed tile visible

    if (tid < 64) {  // merge 4 row-waves -> 128-row partial, store to ws
      float m0 = pmaxb[cur * 256 + tid],       m1 = pmaxb[cur * 256 + 64 + tid];
      float m2 = pmaxb[cur * 256 + 128 + tid], m3 = pmaxb[cur * 256 + 192 + tid];
      float s0 = psumb[cur * 256 + tid],       s1 = psumb[cur * 256 + 64 + tid];
      float s2 = psumb[cur * 256 + 128 + tid], s3 = psumb[cur * 256 + 192 + tid];
      float nm = fmaxf(fmaxf(m0, m1), fmaxf(m2, m3));
      float s = s0 * __expf(m0 - nm) + s1 * __expf(m1 - nm) +
                s2 * __expf(m2 - nm) + s3 * __expf(m3 - nm);
      wmax[(size_t)bx * 512 + et * 64 + tid] = nm;
      wsum[(size_t)bx * 512 + et * 64 + tid] = s;
    }
    // parity double-buffer on pmax/psum: phase et+1 writes parity cur^1,
    // so no barrier needed between this merge-read and the next epilogue.
  }
}

// ---- merge the 4 row-quarters of each b-block, add eterm, sum over cols ----
__global__ void merge_b(const float* __restrict__ wmax, const float* __restrict__ wsum,
                        const float* __restrict__ eterm, float* __restrict__ partial) {
  __shared__ float sh[512];
  const int b = blockIdx.x, t = threadIdx.x;
  float m0 = wmax[(size_t)(4 * b + 0) * 512 + t];
  float m1 = wmax[(size_t)(4 * b + 1) * 512 + t];
  float m2 = wmax[(size_t)(4 * b + 2) * 512 + t];
  float m3 = wmax[(size_t)(4 * b + 3) * 512 + t];
  float s0 = wsum[(size_t)(4 * b + 0) * 512 + t];
  float s1 = wsum[(size_t)(4 * b + 1) * 512 + t];
  float s2 = wsum[(size_t)(4 * b + 2) * 512 + t];
  float s3 = wsum[(size_t)(4 * b + 3) * 512 + t];
  float nm = fmaxf(fmaxf(m0, m1), fmaxf(m2, m3));
  float s = s0 * __expf(m0 - nm) + s1 * __expf(m1 - nm) +
            s2 * __expf(m2 - nm) + s3 * __expf(m3 - nm);
  sh[t] = nm + logf(s) + eterm[t];
  __syncthreads();
  for (int st = 256; st > 0; st >>= 1) {
    if (t < st) sh[t] += sh[t + st];
    __syncthreads();
  }
  if (t == 0) partial[b] = sh[0];
}

__global__ void final_k(const float* __restrict__ partial,
                        const float* __restrict__ lsp, float* __restrict__ out) {
  __shared__ float sh[128];
  const int t = threadIdx.x;
  sh[t] = partial[t];
  __syncthreads();
  for (int st = 64; st > 0; st >>= 1) {
    if (t < st) sh[t] += sh[t + st];
    __syncthreads();
  }
  if (t == 0) {
    float ls = lsp[0];
    out[0] = -sh[0] / 65536.0f + 128.0f * (2.0f * ls - 1.0f) + logf(512.0f);
  }
}

extern "C" void kernel_launch(void* const* d_in, const int* in_sizes, int n_in,
                              void* d_out, int out_size, void* d_ws, size_t ws_size,
                              hipStream_t stream) {
  const float* z   = (const float*)d_in[0];
  const float* e   = (const float*)d_in[1];
  const float* lsp = (const float*)d_in[2];
  float* out = (float*)d_out;
  char* ws = (char*)d_ws;
  char*  eimg    = ws + WS_EIMG;
  float* eterm   = (float*)(ws + WS_ETERM);
  float* wmax    = (float*)(ws + WS_WMAX);
  float* wsum    = (float*)(ws + WS_WSUM);
  float* partial = (float*)(ws + WS_PART);

  hipFuncSetAttribute(reinterpret_cast<const void*>(lse_main),
                      hipFuncAttributeMaxDynamicSharedMemorySize, SMEM_BYTES);
  prep_e<<<dim3(8), dim3(256), 0, stream>>>(e, lsp, eimg, eterm);
  lse_main<<<dim3(512), dim3(512), SMEM_BYTES, stream>>>(z, (const uint4*)eimg, lsp, wmax, wsum);
  merge_b<<<dim3(128), dim3(512), 0, stream>>>(wmax, wsum, eterm, partial);
  final_k<<<dim3(1), dim3(128), 0, stream>>>(partial, lsp, out);
}

// Round 4
// 53.699 us; speedup vs baseline: 2.3684x; 1.4506x over previous
//
#include <hip/hip_runtime.h>
#include <stdint.h>
#include <math.h>

typedef __attribute__((ext_vector_type(8))) short short8;
typedef __attribute__((ext_vector_type(4))) float f32x4;

#define DEVI static __device__ __forceinline__

constexpr int D = 256;  // feature dim

// ws layout (bytes)
constexpr size_t WS_EIMG  = 0;                   // 16 tiles x 16384 = 262144
constexpr size_t WS_ETERM = 262144;              // 512 f32
constexpr size_t WS_WMAX  = 264192;              // 1024 blk x 512 col f32 = 2 MB
constexpr size_t WS_WSUM  = WS_WMAX + 2097152;   // 2 MB
constexpr size_t WS_PART  = WS_WSUM + 2097152;   // 128 f32

DEVI unsigned int f2bf(float f) {
  unsigned int u = __float_as_uint(f);
  return (u + 0x7fffu + ((u >> 16) & 1u)) >> 16;  // RNE f32->bf16 (finite)
}
DEVI float shflx(float v, int m) { return __shfl_xor(v, m, 64); }

// ---- prep: e -> 16 pre-swizzled bf16(a*e) 32-col tile images + eterm ----
// Tile image byte layout: phys = (c*512 + k2*16) ^ ((c&7)<<4), c=0..31 col in
// tile, k2=0..31 the 16B k-granule (8 bf16). 16 blocks x 256 thr.
__global__ void prep_e(const float* __restrict__ e, const float* __restrict__ lsp,
                       char* __restrict__ eimg, float* __restrict__ eterm) {
  const int et = blockIdx.x, t = threadIdx.x;
  const int c = t >> 3, o = t & 7;   // col in tile, octant of 256 k
  const int gc = et * 32 + c;
  const float a = __expf(-2.0f * lsp[0]);
  const float* s = e + (size_t)gc * D + o * 32;
  float sq = 0.0f;
  unsigned int w[16];
#pragma unroll
  for (int i = 0; i < 8; ++i) {
    float4 x = *(const float4*)(s + i * 4);
    sq += x.x * x.x + x.y * x.y + x.z * x.z + x.w * x.w;
    w[2 * i]     = f2bf(a * x.x) | (f2bf(a * x.y) << 16);
    w[2 * i + 1] = f2bf(a * x.z) | (f2bf(a * x.w) << 16);
  }
  sq += shflx(sq, 1); sq += shflx(sq, 2); sq += shflx(sq, 4);  // 8-lane group
  char* base = eimg + (size_t)et * 16384;
#pragma unroll
  for (int g = 0; g < 4; ++g) {
    int k2 = o * 4 + g;
    int phys = (c * 512 + k2 * 16) ^ ((c & 7) << 4);
    uint4 pk; pk.x = w[4 * g]; pk.y = w[4 * g + 1];
    pk.z = w[4 * g + 2]; pk.w = w[4 * g + 3];
    *(uint4*)(base + phys) = pk;
  }
  if (o == 0) eterm[gc] = -0.5f * a * sq;
}

// ---- main: 1024 blocks x 256 thr (4 waves); wave owns 16 z-rows resident in
// A-fragments (32 VGPR). 16 phases over 32-col e-tiles (LDS dbuf). ----
__global__ __launch_bounds__(256, 4)
void lse_main(const float* __restrict__ z, const char* __restrict__ eimg,
              const float* __restrict__ lsp, float* __restrict__ wmax,
              float* __restrict__ wsum) {
  __shared__ char  ebuf[2][16384];
  __shared__ float zterm[64];
  __shared__ float pmaxb[2][4][32];
  __shared__ float psumb[2][4][32];

  const int tid = threadIdx.x;
  const int wid = tid >> 6, lane = tid & 63;
  const int r16 = lane & 15;   // A row within wave / C col
  const int q   = lane >> 4;   // k-quarter / C row-group
  const int bx = blockIdx.x;
  const float a = __expf(-2.0f * lsp[0]);

  uint4 er[4];
  // issue tile-0 e loads first; they land during z staging
#pragma unroll
  for (int i = 0; i < 4; ++i)
    er[i] = *(const uint4*)(eimg + i * 4096 + tid * 16);

  // z -> A fragments. lane: row bx*64 + wid*16 + r16, k = s*32 + q*8 + j.
  // Fenced groups of 2 steps keep <=16 load regs in flight (spill guard).
  short8 A[8];
  const float* zs = z + ((size_t)bx * 64 + wid * 16 + r16) * D + q * 8;
  float sq = 0.0f;
#pragma unroll
  for (int g4 = 0; g4 < 4; ++g4) {
#pragma unroll
    for (int s2 = 0; s2 < 2; ++s2) {
      const int s = g4 * 2 + s2;
      float4 x0 = *(const float4*)(zs + s * 32);
      float4 x1 = *(const float4*)(zs + s * 32 + 4);
      sq += x0.x * x0.x + x0.y * x0.y + x0.z * x0.z + x0.w * x0.w +
            x1.x * x1.x + x1.y * x1.y + x1.z * x1.z + x1.w * x1.w;
      uint4 pk;
      pk.x = f2bf(x0.x) | (f2bf(x0.y) << 16);
      pk.y = f2bf(x0.z) | (f2bf(x0.w) << 16);
      pk.z = f2bf(x1.x) | (f2bf(x1.y) << 16);
      pk.w = f2bf(x1.z) | (f2bf(x1.w) << 16);
      A[s] = __builtin_bit_cast(short8, pk);
    }
    asm volatile("" ::: "memory");
  }
  sq += shflx(sq, 16); sq += shflx(sq, 32);  // full-row ||z||^2
  if (q == 0) zterm[wid * 16 + r16] = -0.5f * a * sq;

#pragma unroll
  for (int i = 0; i < 4; ++i)
    *(uint4*)(&ebuf[0][0] + i * 4096 + tid * 16) = er[i];
  __syncthreads();

  for (int p = 0; p < 16; ++p) {
    const int cur = p & 1;
    if (p < 15) {  // issue next tile's e loads (commit after epilogue)
#pragma unroll
      for (int i = 0; i < 4; ++i)
        er[i] = *(const uint4*)(eimg + (size_t)(p + 1) * 16384 + i * 4096 + tid * 16);
    }

    f32x4 acc0 = {0.f, 0.f, 0.f, 0.f}, acc1 = {0.f, 0.f, 0.f, 0.f};
    const char* bp = &ebuf[cur][0];
#pragma unroll
    for (int s = 0; s < 8; ++s) {
      const int phys = (r16 * 512 + s * 64 + q * 16) ^ ((lane & 7) << 4);
      short8 B0 = *(const short8*)(bp + phys);           // cols 0..15 of tile
      short8 B1 = *(const short8*)(bp + phys + 8192);    // cols 16..31
      acc0 = __builtin_amdgcn_mfma_f32_16x16x32_bf16(A[s], B0, acc0, 0, 0, 0);
      acc1 = __builtin_amdgcn_mfma_f32_16x16x32_bf16(A[s], B1, acc1, 0, 0, 0);
    }

    // epilogue: C col = r16(+16), row = q*4+j. Per-col max/sumexp over 16 rows.
    float zt[4], v0[4], v1[4];
#pragma unroll
    for (int j = 0; j < 4; ++j) zt[j] = zterm[wid * 16 + q * 4 + j];
#pragma unroll
    for (int j = 0; j < 4; ++j) { v0[j] = acc0[j] + zt[j]; v1[j] = acc1[j] + zt[j]; }
    float mx0 = fmaxf(fmaxf(v0[0], v0[1]), fmaxf(v0[2], v0[3]));
    float mx1 = fmaxf(fmaxf(v1[0], v1[1]), fmaxf(v1[2], v1[3]));
    mx0 = fmaxf(mx0, shflx(mx0, 16)); mx0 = fmaxf(mx0, shflx(mx0, 32));
    mx1 = fmaxf(mx1, shflx(mx1, 16)); mx1 = fmaxf(mx1, shflx(mx1, 32));
    float sm0 = __expf(v0[0] - mx0) + __expf(v0[1] - mx0) +
                __expf(v0[2] - mx0) + __expf(v0[3] - mx0);
    float sm1 = __expf(v1[0] - mx1) + __expf(v1[1] - mx1) +
                __expf(v1[2] - mx1) + __expf(v1[3] - mx1);
    sm0 += shflx(sm0, 16); sm0 += shflx(sm0, 32);
    sm1 += shflx(sm1, 16); sm1 += shflx(sm1, 32);
    if (q == 0) {
      pmaxb[cur][wid][r16] = mx0;      psumb[cur][wid][r16] = sm0;
      pmaxb[cur][wid][16 + r16] = mx1; psumb[cur][wid][16 + r16] = sm1;
    }
    if (p < 15) {  // commit next e-tile into the other buffer
#pragma unroll
      for (int i = 0; i < 4; ++i)
        *(uint4*)(&ebuf[cur ^ 1][0] + i * 4096 + tid * 16) = er[i];
    }
    __syncthreads();  // pmax/psum + committed tile visible; all reads done

    if (tid < 32) {  // merge 4 waves -> 64-row block partial, store to ws
      float m0 = pmaxb[cur][0][tid], m1 = pmaxb[cur][1][tid];
      float m2 = pmaxb[cur][2][tid], m3 = pmaxb[cur][3][tid];
      float nm = fmaxf(fmaxf(m0, m1), fmaxf(m2, m3));
      float s = psumb[cur][0][tid] * __expf(m0 - nm) +
                psumb[cur][1][tid] * __expf(m1 - nm) +
                psumb[cur][2][tid] * __expf(m2 - nm) +
                psumb[cur][3][tid] * __expf(m3 - nm);
      wmax[(size_t)bx * 512 + p * 32 + tid] = nm;
      wsum[(size_t)bx * 512 + p * 32 + tid] = s;
    }
    // parity dbuf on pmax/psum: phase p+1 writes parity cur^1, and phase p+2's
    // writes to parity cur happen only after barrier(p+1) -> merge is safe.
  }
}

// ---- merge 8 main-blocks per 512-row b-block, add eterm, sum over cols ----
__global__ void merge_b(const float* __restrict__ wmax, const float* __restrict__ wsum,
                        const float* __restrict__ eterm, float* __restrict__ partial) {
  __shared__ float sh[512];
  const int b = blockIdx.x, t = threadIdx.x;
  float m[8];
  float nm = -1e30f;
#pragma unroll
  for (int i = 0; i < 8; ++i) {
    m[i] = wmax[(size_t)(8 * b + i) * 512 + t];
    nm = fmaxf(nm, m[i]);
  }
  float s = 0.0f;
#pragma unroll
  for (int i = 0; i < 8; ++i)
    s += wsum[(size_t)(8 * b + i) * 512 + t] * __expf(m[i] - nm);
  sh[t] = nm + logf(s) + eterm[t];
  __syncthreads();
  for (int st = 256; st > 0; st >>= 1) {
    if (t < st) sh[t] += sh[t + st];
    __syncthreads();
  }
  if (t == 0) partial[b] = sh[0];
}

__global__ void final_k(const float* __restrict__ partial,
                        const float* __restrict__ lsp, float* __restrict__ out) {
  __shared__ float sh[128];
  const int t = threadIdx.x;
  sh[t] = partial[t];
  __syncthreads();
  for (int st = 64; st > 0; st >>= 1) {
    if (t < st) sh[t] += sh[t + st];
    __syncthreads();
  }
  if (t == 0) {
    float ls = lsp[0];
    out[0] = -sh[0] / 65536.0f + 128.0f * (2.0f * ls - 1.0f) + logf(512.0f);
  }
}

extern "C" void kernel_launch(void* const* d_in, const int* in_sizes, int n_in,
                              void* d_out, int out_size, void* d_ws, size_t ws_size,
                              hipStream_t stream) {
  const float* z   = (const float*)d_in[0];
  const float* e   = (const float*)d_in[1];
  const float* lsp = (const float*)d_in[2];
  float* out = (float*)d_out;
  char* ws = (char*)d_ws;
  char*  eimg    = ws + WS_EIMG;
  float* eterm   = (float*)(ws + WS_ETERM);
  float* wmax    = (float*)(ws + WS_WMAX);
  float* wsum    = (float*)(ws + WS_WSUM);
  float* partial = (float*)(ws + WS_PART);

  prep_e<<<dim3(16), dim3(256), 0, stream>>>(e, lsp, eimg, eterm);
  lse_main<<<dim3(1024), dim3(256), 0, stream>>>(z, eimg, lsp, wmax, wsum);
  merge_b<<<dim3(128), dim3(512), 0, stream>>>(wmax, wsum, eterm, partial);
  final_k<<<dim3(1), dim3(128), 0, stream>>>(partial, lsp, out);
}

// Round 5
// 45.493 us; speedup vs baseline: 2.7956x; 1.1804x over previous
//
#include <hip/hip_runtime.h>
#include <stdint.h>
#include <math.h>

typedef __attribute__((ext_vector_type(8))) short short8;
typedef __attribute__((ext_vector_type(16))) float f32x16;

#define DEVI static __device__ __forceinline__

constexpr int D = 256;  // feature dim

// ws layout (bytes)
constexpr size_t WS_EIMG  = 0;                   // 16 tiles x 16384 = 262144
constexpr size_t WS_ETERM = 262144;              // 512 f32
constexpr size_t WS_WMAX  = 264192;              // 512 blk x 512 col f32 = 1 MB
constexpr size_t WS_WSUM  = WS_WMAX + 1048576;   // 1 MB
constexpr size_t WS_PART  = WS_WSUM + 1048576;   // 128 f32

DEVI unsigned int f2bf(float f) {
  unsigned int u = __float_as_uint(f);
  return (u + 0x7fffu + ((u >> 16) & 1u)) >> 16;  // RNE f32->bf16 (finite)
}
DEVI float shflx(float v, int m) { return __shfl_xor(v, m, 64); }

// ---- prep: e -> 16 pre-swizzled bf16(a*e) 32-col tile images + eterm ----
// Tile image byte layout: phys = (c*512 + k2*16) ^ ((c&7)<<4), c=0..31 col in
// tile, k2=0..31 the 16B k-granule (8 bf16). 16 blocks x 256 thr.
__global__ void prep_e(const float* __restrict__ e, const float* __restrict__ lsp,
                       char* __restrict__ eimg, float* __restrict__ eterm) {
  const int et = blockIdx.x, t = threadIdx.x;
  const int c = t >> 3, o = t & 7;   // col in tile, octant of 256 k
  const int gc = et * 32 + c;
  const float a = __expf(-2.0f * lsp[0]);
  const float* s = e + (size_t)gc * D + o * 32;
  float sq = 0.0f;
  unsigned int w[16];
#pragma unroll
  for (int i = 0; i < 8; ++i) {
    float4 x = *(const float4*)(s + i * 4);
    sq += x.x * x.x + x.y * x.y + x.z * x.z + x.w * x.w;
    w[2 * i]     = f2bf(a * x.x) | (f2bf(a * x.y) << 16);
    w[2 * i + 1] = f2bf(a * x.z) | (f2bf(a * x.w) << 16);
  }
  sq += shflx(sq, 1); sq += shflx(sq, 2); sq += shflx(sq, 4);  // 8-lane group
  char* base = eimg + (size_t)et * 16384;
#pragma unroll
  for (int g = 0; g < 4; ++g) {
    int k2 = o * 4 + g;
    int phys = (c * 512 + k2 * 16) ^ ((c & 7) << 4);
    uint4 pk; pk.x = w[4 * g]; pk.y = w[4 * g + 1];
    pk.z = w[4 * g + 2]; pk.w = w[4 * g + 3];
    *(uint4*)(base + phys) = pk;
  }
  if (o == 0) eterm[gc] = -0.5f * a * sq;
}

// ---- main: 512 blocks x 256 thr (4 waves); wave owns 32 z-rows resident in
// A-fragments (64 VGPR, 32x32x16 MFMA). 16 phases over 32-col e-tiles. ----
__global__ __launch_bounds__(256, 2)
void lse_main(const float* __restrict__ z, const char* __restrict__ eimg,
              const float* __restrict__ lsp, float* __restrict__ wmax,
              float* __restrict__ wsum) {
  __shared__ char  ebuf[2][16384];
  __shared__ float zterm[128];
  __shared__ float pmaxb[2][4][32];
  __shared__ float psumb[2][4][32];

  const int tid = threadIdx.x;
  const int wid = tid >> 6, lane = tid & 63;
  const int l31 = lane & 31;   // A row within wave / C col (e-col)
  const int hi  = lane >> 5;   // k-half of A/B frag; C row-group bit
  const int bx = blockIdx.x;
  const float a = __expf(-2.0f * lsp[0]);

  uint4 er[4];
  // issue tile-0 e loads first; they land during z staging
#pragma unroll
  for (int i = 0; i < 4; ++i)
    er[i] = *(const uint4*)(eimg + i * 4096 + tid * 16);

  // z -> A fragments (32x32x16 layout): lane holds row bx*128 + wid*32 + l31,
  // k = s*16 + hi*8 + j. Fenced groups of 2 steps keep load-reg pressure low.
  short8 A[16];
  const float* zs = z + ((size_t)bx * 128 + wid * 32 + l31) * D + hi * 8;
  float sq = 0.0f;
#pragma unroll
  for (int g = 0; g < 8; ++g) {
#pragma unroll
    for (int s2 = 0; s2 < 2; ++s2) {
      const int s = g * 2 + s2;
      float4 x0 = *(const float4*)(zs + s * 16);
      float4 x1 = *(const float4*)(zs + s * 16 + 4);
      sq += x0.x * x0.x + x0.y * x0.y + x0.z * x0.z + x0.w * x0.w +
            x1.x * x1.x + x1.y * x1.y + x1.z * x1.z + x1.w * x1.w;
      uint4 pk;
      pk.x = f2bf(x0.x) | (f2bf(x0.y) << 16);
      pk.y = f2bf(x0.z) | (f2bf(x0.w) << 16);
      pk.z = f2bf(x1.x) | (f2bf(x1.y) << 16);
      pk.w = f2bf(x1.z) | (f2bf(x1.w) << 16);
      A[s] = __builtin_bit_cast(short8, pk);
    }
    asm volatile("" ::: "memory");
  }
  sq += shflx(sq, 32);  // partner lane holds the other k-half of the same row
  if (hi == 0) zterm[wid * 32 + l31] = -0.5f * a * sq;

#pragma unroll
  for (int i = 0; i < 4; ++i)
    *(uint4*)(&ebuf[0][0] + i * 4096 + tid * 16) = er[i];
  __syncthreads();

  // hoist zterm for this lane's 16 C-rows: row = (r&3) + 8*(r>>2) + 4*hi
  float zt[16];
#pragma unroll
  for (int r = 0; r < 16; ++r)
    zt[r] = zterm[wid * 32 + (r & 3) + 8 * (r >> 2) + 4 * hi];

  const int cbase = l31 * 512;          // e-col row in tile image
  const int key = (l31 & 7) << 4;       // swizzle key (applies to low 9 bits)

  for (int p = 0; p < 16; ++p) {
    const int cur = p & 1;
    if (p < 15) {  // issue next tile's e loads (commit after epilogue)
#pragma unroll
      for (int i = 0; i < 4; ++i)
        er[i] = *(const uint4*)(eimg + (size_t)(p + 1) * 16384 + i * 4096 + tid * 16);
    }

    f32x16 acc;
#pragma unroll
    for (int i = 0; i < 16; ++i) acc[i] = 0.0f;
    const char* bp = &ebuf[cur][0];
#pragma unroll
    for (int s = 0; s < 16; ++s) {
      // B frag: col=l31, k = s*16 + hi*8 + j -> granule k2 = 2s + hi
      short8 B = *(const short8*)(bp + cbase + (((2 * s + hi) * 16) ^ key));
      acc = __builtin_amdgcn_mfma_f32_32x32x16_bf16(A[s], B, acc, 0, 0, 0);
    }

    // epilogue: lane has one e-col (l31), 16 z-rows. LSE partial over 32 rows.
    float mx = -1e30f;
#pragma unroll
    for (int r = 0; r < 16; ++r) {
      acc[r] += zt[r];
      mx = fmaxf(mx, acc[r]);
    }
    mx = fmaxf(mx, shflx(mx, 32));  // other 16 rows live in partner lane
    float sme = 0.0f;
#pragma unroll
    for (int r = 0; r < 16; ++r) sme += __expf(acc[r] - mx);
    sme += shflx(sme, 32);
    if (hi == 0) {
      pmaxb[cur][wid][l31] = mx;
      psumb[cur][wid][l31] = sme;
    }
    if (p < 15) {  // commit next e-tile into the other buffer
#pragma unroll
      for (int i = 0; i < 4; ++i)
        *(uint4*)(&ebuf[cur ^ 1][0] + i * 4096 + tid * 16) = er[i];
    }
    __syncthreads();  // pmax/psum + committed tile visible; all reads done

    if (tid < 32) {  // merge 4 waves -> 128-row block partial, store to ws
      float m0 = pmaxb[cur][0][tid], m1 = pmaxb[cur][1][tid];
      float m2 = pmaxb[cur][2][tid], m3 = pmaxb[cur][3][tid];
      float nm = fmaxf(fmaxf(m0, m1), fmaxf(m2, m3));
      float s = psumb[cur][0][tid] * __expf(m0 - nm) +
                psumb[cur][1][tid] * __expf(m1 - nm) +
                psumb[cur][2][tid] * __expf(m2 - nm) +
                psumb[cur][3][tid] * __expf(m3 - nm);
      wmax[(size_t)bx * 512 + p * 32 + tid] = nm;
      wsum[(size_t)bx * 512 + p * 32 + tid] = s;
    }
    // parity dbuf on pmax/psum: phase p+1 writes parity cur^1; phase p+2's
    // writes to parity cur happen only after barrier(p+1) -> merge is safe.
  }
}

// ---- merge 4 main-blocks per 512-row b-block, add eterm, sum over cols ----
__global__ void merge_b(const float* __restrict__ wmax, const float* __restrict__ wsum,
                        const float* __restrict__ eterm, float* __restrict__ partial) {
  __shared__ float sh[512];
  const int b = blockIdx.x, t = threadIdx.x;
  float m[4];
  float nm = -1e30f;
#pragma unroll
  for (int i = 0; i < 4; ++i) {
    m[i] = wmax[(size_t)(4 * b + i) * 512 + t];
    nm = fmaxf(nm, m[i]);
  }
  float s = 0.0f;
#pragma unroll
  for (int i = 0; i < 4; ++i)
    s += wsum[(size_t)(4 * b + i) * 512 + t] * __expf(m[i] - nm);
  sh[t] = nm + logf(s) + eterm[t];
  __syncthreads();
  for (int st = 256; st > 0; st >>= 1) {
    if (t < st) sh[t] += sh[t + st];
    __syncthreads();
  }
  if (t == 0) partial[b] = sh[0];
}

__global__ void final_k(const float* __restrict__ partial,
                        const float* __restrict__ lsp, float* __restrict__ out) {
  __shared__ float sh[128];
  const int t = threadIdx.x;
  sh[t] = partial[t];
  __syncthreads();
  for (int st = 64; st > 0; st >>= 1) {
    if (t < st) sh[t] += sh[t + st];
    __syncthreads();
  }
  if (t == 0) {
    float ls = lsp[0];
    out[0] = -sh[0] / 65536.0f + 128.0f * (2.0f * ls - 1.0f) + logf(512.0f);
  }
}

extern "C" void kernel_launch(void* const* d_in, const int* in_sizes, int n_in,
                              void* d_out, int out_size, void* d_ws, size_t ws_size,
                              hipStream_t stream) {
  const float* z   = (const float*)d_in[0];
  const float* e   = (const float*)d_in[1];
  const float* lsp = (const float*)d_in[2];
  float* out = (float*)d_out;
  char* ws = (char*)d_ws;
  char*  eimg    = ws + WS_EIMG;
  float* eterm   = (float*)(ws + WS_ETERM);
  float* wmax    = (float*)(ws + WS_WMAX);
  float* wsum    = (float*)(ws + WS_WSUM);
  float* partial = (float*)(ws + WS_PART);

  prep_e<<<dim3(16), dim3(256), 0, stream>>>(e, lsp, eimg, eterm);
  lse_main<<<dim3(512), dim3(256), 0, stream>>>(z, eimg, lsp, wmax, wsum);
  merge_b<<<dim3(128), dim3(512), 0, stream>>>(wmax, wsum, eterm, partial);
  final_k<<<dim3(1), dim3(128), 0, stream>>>(partial, lsp, out);
}